// Round 3
// baseline (354.886 us; speedup 1.0000x reference)
//
#include <hip/hip_runtime.h>

// Fused CircularBoundaryBlock:
//   out = relu(LN(x + W2 @ relu(W1 @ [roll(x,1), x, roll(x,-1)] + b1) + b2))
// B=4, N=65536, H=128, fp32 I/O, bf16 MFMA internally.
//
// v4: occupancy via narrower column slices.
//   - 512-thread blocks, 8 waves, wave w owns cols [16w, 16w+16).
//   - W1 frags: 12 regs-of-8 (48 regs), W2 frags: 4 (16 regs) — both in
//     registers; no w2s LDS (back to ~37 KB LDS).
//   - Per-thread total ~125 regs -> __launch_bounds__(512,4) -> 4 waves/SIMD
//     = 16 waves/CU (2 blocks/CU), 2x v3's latency hiding. No weight
//     streaming (v2's HBM-inflation failure mode avoided).
//   - T14 stage split kept; halo rows now prefetched too (v3 had a sync
//     HBM load on the critical path each iteration).
//   - GEMM1 interchanged to ks-outer/rt-inner: 4-way interleaved MFMA
//     accumulation chains instead of 12-deep.

typedef __bf16 bf16x8 __attribute__((ext_vector_type(8)));
typedef __bf16 bf16x4 __attribute__((ext_vector_type(4)));
typedef float  f32x4  __attribute__((ext_vector_type(4)));

#define H      128
#define NB     65536        // rows per batch
#define TILE   64
#define XS     136          // x LDS stride (bf16 elems): 68 words ≡ 4 mod 32
#define HSS    136          // h LDS stride (bf16 elems)
#define VS     132          // v LDS stride (f32 elems)
#define NTILES 4096         // 4 * 65536 / 64
#define GRID   512          // 2 blocks/CU * 256 CUs
#define BLK    512          // threads per block (8 waves)

__global__ __launch_bounds__(BLK, 4)
void cbb_kernel(const float* __restrict__ x, const float* __restrict__ W1,
                const float* __restrict__ b1, const float* __restrict__ W2,
                const float* __restrict__ b2, const float* __restrict__ gamma,
                const float* __restrict__ beta, float* __restrict__ out) {
    // region A: xs (66*136 bf16) + hs (64*136 bf16) = 35360 B
    // region B (aliased): vs (64*132 f32) = 33792 B
    __shared__ __align__(16) char raw[(66 * XS + 64 * HSS) * 2];
    __bf16* xs = (__bf16*)raw;
    __bf16* hs = xs + 66 * XS;
    float*  vs = (float*)raw;
    __shared__ float s_mu[64], s_rs[64], s_gamma[128], s_beta[128];

    const int tid  = threadIdx.x;
    const int wid  = tid >> 6;        // 0..7
    const int lane = tid & 63;
    const int l    = lane & 15;       // MFMA m / n index
    const int g    = lane >> 4;       // MFMA quad (k-chunk select)
    const int col0 = wid * 16;        // 16-col slice per wave
    const int c0   = col0 + l;

    if (tid < 128) { s_gamma[tid] = gamma[tid]; s_beta[tid] = beta[tid]; }

    const float b1r0 = b1[c0];
    const float b2r0 = b2[c0];

    // ---- persistent weight B-fragments (bf16), this wave's 16-col slice ----
    bf16x8 w1f[12];
#pragma unroll
    for (int ks = 0; ks < 12; ++ks) {
        bf16x8 f;
#pragma unroll
        for (int j = 0; j < 8; ++j)
            f[j] = (__bf16)W1[(ks * 32 + g * 8 + j) * H + c0];
        w1f[ks] = f;
    }
    bf16x8 w2f[4];
#pragma unroll
    for (int ks = 0; ks < 4; ++ks) {
        bf16x8 f;
#pragma unroll
        for (int j = 0; j < 8; ++j)
            f[j] = (__bf16)W2[(ks * 32 + g * 8 + j) * H + c0];
        w2f[ks] = f;
    }

    // ---- T14 prefetch: full 66-row halo tile (4 slots/thread + tid<64 halo) ----
    float4 xreg[4];
    float4 xhalo;
    {
        const int t  = blockIdx.x;
        const int b  = t >> 10;
        const int n0 = (t & 1023) << 6;
        const size_t rowbase = (size_t)b * NB;
#pragma unroll
        for (int s = 0; s < 4; ++s) {
            const int q = tid + s * BLK;            // q < 2048 -> rows 0..63
            const int r = q >> 5, c = q & 31;
            const int grow = (n0 - 1 + r + NB) & (NB - 1);
            xreg[s] = *(const float4*)(x + ((rowbase + grow) * H + c * 4));
        }
        if (tid < 64) {                              // rows 64,65
            const int q = 2048 + tid;
            const int r = q >> 5, c = q & 31;
            const int grow = (n0 - 1 + r + NB) & (NB - 1);
            xhalo = *(const float4*)(x + ((rowbase + grow) * H + c * 4));
        }
    }

    for (int t = blockIdx.x; t < NTILES; t += GRID) {
        const int b  = t >> 10;
        const int n0 = (t & 1023) << 6;
        const size_t rowbase = (size_t)b * NB;

        __syncthreads();  // protect vs (aliases xs) from previous iteration readers

        // ---- stage: consume prefetched regs -> xs (bf16) ----
#pragma unroll
        for (int s = 0; s < 4; ++s) {
            const int q = tid + s * BLK;
            const int r = q >> 5, c = q & 31;
            bf16x4 v4;
            v4[0] = (__bf16)xreg[s].x; v4[1] = (__bf16)xreg[s].y;
            v4[2] = (__bf16)xreg[s].z; v4[3] = (__bf16)xreg[s].w;
            *(bf16x4*)(xs + r * XS + c * 4) = v4;
        }
        if (tid < 64) {
            const int q = 2048 + tid;
            const int r = q >> 5, c = q & 31;
            bf16x4 v4;
            v4[0] = (__bf16)xhalo.x; v4[1] = (__bf16)xhalo.y;
            v4[2] = (__bf16)xhalo.z; v4[3] = (__bf16)xhalo.w;
            *(bf16x4*)(xs + r * XS + c * 4) = v4;
        }
        __syncthreads();

        // ---- issue next tile's loads; they fly under GEMM1/GEMM2/LN ----
        if (t + GRID < NTILES) {
            const int tn  = t + GRID;
            const int bn  = tn >> 10;
            const int n0n = (tn & 1023) << 6;
            const size_t rbn = (size_t)bn * NB;
#pragma unroll
            for (int s = 0; s < 4; ++s) {
                const int q = tid + s * BLK;
                const int r = q >> 5, c = q & 31;
                const int grow = (n0n - 1 + r + NB) & (NB - 1);
                xreg[s] = *(const float4*)(x + ((rbn + grow) * H + c * 4));
            }
            if (tid < 64) {
                const int q = 2048 + tid;
                const int r = q >> 5, c = q & 31;
                const int grow = (n0n - 1 + r + NB) & (NB - 1);
                xhalo = *(const float4*)(x + ((rbn + grow) * H + c * 4));
            }
        }

        // ---- GEMM1: h = relu(cat @ W1 + b1), ks-outer / rt-inner ----
        f32x4 acc[4];
#pragma unroll
        for (int rt = 0; rt < 4; ++rt)
            acc[rt] = (f32x4){0.f, 0.f, 0.f, 0.f};

#pragma unroll
        for (int ks = 0; ks < 12; ++ks) {
            const int k = ks * 32 + g * 8;              // k in [0,384)
#pragma unroll
            for (int rt = 0; rt < 4; ++rt) {
                const bf16x8 a = *(const bf16x8*)(xs + (rt * 16 + l + (k >> 7)) * XS + (k & 127));
                acc[rt] = __builtin_amdgcn_mfma_f32_16x16x32_bf16(a, w1f[ks], acc[rt], 0, 0, 0);
            }
        }

        // relu + bias -> hs (bf16, row-major), C-layout scatter
#pragma unroll
        for (int rt = 0; rt < 4; ++rt) {
#pragma unroll
            for (int i = 0; i < 4; ++i) {
                const int row = rt * 16 + g * 4 + i;
                hs[row * HSS + c0] = (__bf16)fmaxf(acc[rt][i] + b1r0, 0.f);
            }
        }
        __syncthreads();

        // ---- GEMM2: delta = h @ W2 ----
        f32x4 acc2[4];
#pragma unroll
        for (int rt = 0; rt < 4; ++rt)
            acc2[rt] = (f32x4){0.f, 0.f, 0.f, 0.f};

#pragma unroll
        for (int ks = 0; ks < 4; ++ks) {
#pragma unroll
            for (int rt = 0; rt < 4; ++rt) {
                const bf16x8 a = *(const bf16x8*)(hs + (rt * 16 + l) * HSS + ks * 32 + g * 8);
                acc2[rt] = __builtin_amdgcn_mfma_f32_16x16x32_bf16(a, w2f[ks], acc2[rt], 0, 0, 0);
            }
        }

        // ---- residual: v = x + delta + b2 (x from bf16 LDS tile, row+1) ----
#pragma unroll
        for (int rt = 0; rt < 4; ++rt) {
#pragma unroll
            for (int i = 0; i < 4; ++i) {
                const int row = rt * 16 + g * 4 + i;
                acc2[rt][i] += b2r0 + (float)xs[(row + 1) * XS + c0];
            }
        }
        __syncthreads();  // all xs/hs reads done; vs may now clobber them

#pragma unroll
        for (int rt = 0; rt < 4; ++rt) {
#pragma unroll
            for (int i = 0; i < 4; ++i) {
                const int row = rt * 16 + g * 4 + i;
                vs[row * VS + c0] = acc2[rt][i];
            }
        }
        __syncthreads();

        // ---- LN stats: 8 threads per row ----
        {
            const int row = tid >> 3;
            const int cb  = (tid & 7) * 16;
            float s = 0.f, qq = 0.f;
#pragma unroll
            for (int c8 = 0; c8 < 4; ++c8) {
                const f32x4 vv = *(const f32x4*)(vs + row * VS + cb + c8 * 4);
#pragma unroll
                for (int e = 0; e < 4; ++e) { s += vv[e]; qq += vv[e] * vv[e]; }
            }
            s  += __shfl_xor(s, 1, 8);  s  += __shfl_xor(s, 2, 8);  s  += __shfl_xor(s, 4, 8);
            qq += __shfl_xor(qq, 1, 8); qq += __shfl_xor(qq, 2, 8); qq += __shfl_xor(qq, 4, 8);
            const float muv = s * (1.f / 128.f);
            const float var = qq * (1.f / 128.f) - muv * muv;
            if ((tid & 7) == 0) { s_mu[row] = muv; s_rs[row] = rsqrtf(var + 1e-5f); }
        }
        __syncthreads();

        // ---- normalize + relu + coalesced float4 store ----
        {
            const int row = tid >> 3;
            const int cb  = (tid & 7) * 16;
            const float muv = s_mu[row], rv = s_rs[row];
            float* op = out + (rowbase + n0 + row) * H + cb;
#pragma unroll
            for (int c8 = 0; c8 < 4; ++c8) {
                const f32x4 vv = *(const f32x4*)(vs + row * VS + cb + c8 * 4);
                const f32x4 gm = *(const f32x4*)(s_gamma + cb + c8 * 4);
                const f32x4 bt = *(const f32x4*)(s_beta + cb + c8 * 4);
                f32x4 o;
#pragma unroll
                for (int e = 0; e < 4; ++e)
                    o[e] = fmaxf((vv[e] - muv) * rv * gm[e] + bt[e], 0.f);
                *(f32x4*)(op + c8 * 4) = o;
            }
        }
    }
}

extern "C" void kernel_launch(void* const* d_in, const int* in_sizes, int n_in,
                              void* d_out, int out_size, void* d_ws, size_t ws_size,
                              hipStream_t stream) {
    const float* x     = (const float*)d_in[0];
    const float* W1    = (const float*)d_in[1];
    const float* b1    = (const float*)d_in[2];
    const float* W2    = (const float*)d_in[3];
    const float* b2    = (const float*)d_in[4];
    const float* gamma = (const float*)d_in[5];
    const float* beta  = (const float*)d_in[6];
    float* out = (float*)d_out;

    // 512 blocks of 512 threads = 2 resident blocks/CU; grid-stride over 4096 tiles
    cbb_kernel<<<GRID, BLK, 0, stream>>>(x, W1, b1, W2, b2, gamma, beta, out);
}

// Round 4
// 264.617 us; speedup vs baseline: 1.3411x; 1.3411x over previous
//
#include <hip/hip_runtime.h>

// Fused CircularBoundaryBlock:
//   out = relu(LN(x + W2 @ relu(W1 @ [roll(x,1), x, roll(x,-1)] + b1) + b2))
// B=4, N=65536, H=128, fp32 I/O, bf16 MFMA internally.
//
// v5 = v3 (best, 110us/dispatch) + serial-chain cuts. v2/v4 proved occupancy
// >8 waves/CU is not purchasable (register wall -> spills); so shorten the
// per-iteration chain instead:
//   - LN fused: shuffle-reduce already gives stats in all 4 lanes/row; drop
//     s_mu/s_rs round-trip, drop barrier B5, read vs ONCE into regs.
//   - VS=133 (odd, ==5 mod 32) + interleaved LN chunk mapping (thread q owns
//     words q*4 + 16*c8): kills the 8-way bank collapse of the old mapping.
//   - halo rows prefetched (v3 had a sync L3 load on the chain every iter).
//   - GEMM1 ks-outer/rt-inner: 8 interleaved MFMA chains, not 12-deep.
//   - s_setprio(1) around MFMA clusters (T5; 2 independent blocks/CU = phase
//     diversity regime where it pays).
// Structure otherwise identical to v3: W1 frags persistent in regs (96),
// W2 frags in LDS (32 KB), T14 stage split, 256 thr, 512 blocks, 2 blk/CU.

typedef __bf16 bf16x8 __attribute__((ext_vector_type(8)));
typedef __bf16 bf16x4 __attribute__((ext_vector_type(4)));
typedef float  f32x4  __attribute__((ext_vector_type(4)));

#define H      128
#define NB     65536        // rows per batch
#define TILE   64
#define XS     136          // x LDS stride (bf16 elems): 68 words == 4 mod 32
#define HSS    136          // h LDS stride (bf16 elems)
#define VS     133          // v LDS stride (f32 elems), odd: 5 mod 32
#define NTILES 4096         // 4 * 65536 / 64
#define GRID   512          // 2 blocks/CU * 256 CUs

__global__ __launch_bounds__(256, 2)
void cbb_kernel(const float* __restrict__ x, const float* __restrict__ W1,
                const float* __restrict__ b1, const float* __restrict__ W2,
                const float* __restrict__ b2, const float* __restrict__ gamma,
                const float* __restrict__ beta, float* __restrict__ out) {
    // region A: xs (66*136 bf16) + hs (64*136 bf16) = 35360 B
    // region B (aliased): vs (64*133 f32) = 34048 B <= 35360 OK
    __shared__ __align__(16) char raw[(66 * XS + 64 * HSS) * 2];
    __bf16* xs = (__bf16*)raw;
    __bf16* hs = xs + 66 * XS;
    float*  vs = (float*)raw;
    __shared__ __align__(16) __bf16 w2s[16384];   // W2 frags, 32 KB, persistent
    __shared__ float s_gamma[128], s_beta[128];

    const int tid  = threadIdx.x;
    const int wid  = tid >> 6;
    const int lane = tid & 63;
    const int l    = lane & 15;   // MFMA m / n index
    const int g    = lane >> 4;   // MFMA quad (k-chunk select)
    const int col0 = wid * 32;
    const int c0   = col0 + l;
    const int c1   = col0 + 16 + l;

    if (tid < 128) { s_gamma[tid] = gamma[tid]; s_beta[tid] = beta[tid]; }

    const float b1r0 = b1[c0], b1r1 = b1[c1];
    const float b2r0 = b2[c0], b2r1 = b2[c1];

    // ---- W1 B-fragments persistent in registers (this wave's 32-col slice) ----
    bf16x8 w1f[12][2];
#pragma unroll
    for (int ks = 0; ks < 12; ++ks) {
#pragma unroll
        for (int ct = 0; ct < 2; ++ct) {
            const int cc = col0 + ct * 16 + l;
            bf16x8 f;
#pragma unroll
            for (int j = 0; j < 8; ++j)
                f[j] = (__bf16)W1[(ks * 32 + g * 8 + j) * H + cc];
            w1f[ks][ct] = f;
        }
    }

    // ---- W2 B-fragments -> LDS, fragment-ordered (once per block) ----
    // layout: w2s[w*4096 + ks*1024 + ct*512 + lane*8 + j]
    for (int idx = tid; idx < 16384; idx += 256) {
        const int j  = idx & 7;
        const int ln = (idx >> 3) & 63;
        const int ct = (idx >> 9) & 1;
        const int ks = (idx >> 10) & 3;
        const int w  = idx >> 12;
        const int row = ks * 32 + (ln >> 4) * 8 + j;
        const int col = w * 32 + ct * 16 + (ln & 15);
        w2s[idx] = (__bf16)W2[row * H + col];
    }
    const __bf16* w2w = w2s + wid * 4096;

    // ---- T14 prefetch: full 66-row halo tile (8 float4 + tid<64 halo) ----
    float4 xreg[8];
    float4 xhalo;
    {
        const int t  = blockIdx.x;
        const int b  = t >> 10;
        const int n0 = (t & 1023) << 6;
        const size_t rowbase = (size_t)b * NB;
#pragma unroll
        for (int s = 0; s < 8; ++s) {
            const int q = tid + s * 256;            // q < 2048 -> rows 0..63
            const int r = q >> 5, c = q & 31;
            const int grow = (n0 - 1 + r + NB) & (NB - 1);
            xreg[s] = *(const float4*)(x + ((rowbase + grow) * H + c * 4));
        }
        if (tid < 64) {                              // rows 64,65
            const int q = 2048 + tid;
            const int r = q >> 5, c = q & 31;
            const int grow = (n0 - 1 + r + NB) & (NB - 1);
            xhalo = *(const float4*)(x + ((rowbase + grow) * H + c * 4));
        }
    }

    for (int t = blockIdx.x; t < NTILES; t += GRID) {
        const int b  = t >> 10;
        const int n0 = (t & 1023) << 6;
        const size_t rowbase = (size_t)b * NB;

        __syncthreads();  // protect vs (aliases xs) from previous iteration readers

        // ---- stage: consume prefetched regs -> xs (bf16) ----
#pragma unroll
        for (int s = 0; s < 8; ++s) {
            const int q = tid + s * 256;
            const int r = q >> 5, c = q & 31;
            bf16x4 v4;
            v4[0] = (__bf16)xreg[s].x; v4[1] = (__bf16)xreg[s].y;
            v4[2] = (__bf16)xreg[s].z; v4[3] = (__bf16)xreg[s].w;
            *(bf16x4*)(xs + r * XS + c * 4) = v4;
        }
        if (tid < 64) {
            const int q = 2048 + tid;
            const int r = q >> 5, c = q & 31;
            bf16x4 v4;
            v4[0] = (__bf16)xhalo.x; v4[1] = (__bf16)xhalo.y;
            v4[2] = (__bf16)xhalo.z; v4[3] = (__bf16)xhalo.w;
            *(bf16x4*)(xs + r * XS + c * 4) = v4;
        }
        __syncthreads();

        // ---- issue next tile's loads; they fly under GEMM1/GEMM2/LN ----
        if (t + GRID < NTILES) {
            const int tn  = t + GRID;
            const int bn  = tn >> 10;
            const int n0n = (tn & 1023) << 6;
            const size_t rbn = (size_t)bn * NB;
#pragma unroll
            for (int s = 0; s < 8; ++s) {
                const int q = tid + s * 256;
                const int r = q >> 5, c = q & 31;
                const int grow = (n0n - 1 + r + NB) & (NB - 1);
                xreg[s] = *(const float4*)(x + ((rbn + grow) * H + c * 4));
            }
            if (tid < 64) {
                const int q = 2048 + tid;
                const int r = q >> 5, c = q & 31;
                const int grow = (n0n - 1 + r + NB) & (NB - 1);
                xhalo = *(const float4*)(x + ((rbn + grow) * H + c * 4));
            }
        }

        // ---- GEMM1: h = relu(cat @ W1 + b1), ks-outer / rt-inner ----
        f32x4 acc[4][2];
#pragma unroll
        for (int rt = 0; rt < 4; ++rt)
#pragma unroll
            for (int ct = 0; ct < 2; ++ct)
                acc[rt][ct] = (f32x4){0.f, 0.f, 0.f, 0.f};

        __builtin_amdgcn_s_setprio(1);
#pragma unroll
        for (int ks = 0; ks < 12; ++ks) {
            const int k  = ks * 32 + g * 8;          // k in [0,384)
            const int ro = k >> 7, kc = k & 127;
#pragma unroll
            for (int rt = 0; rt < 4; ++rt) {
                const bf16x8 a = *(const bf16x8*)(xs + (rt * 16 + l + ro) * XS + kc);
                acc[rt][0] = __builtin_amdgcn_mfma_f32_16x16x32_bf16(a, w1f[ks][0], acc[rt][0], 0, 0, 0);
                acc[rt][1] = __builtin_amdgcn_mfma_f32_16x16x32_bf16(a, w1f[ks][1], acc[rt][1], 0, 0, 0);
            }
        }
        __builtin_amdgcn_s_setprio(0);

        // relu + bias -> hs (bf16, row-major), C-layout scatter
#pragma unroll
        for (int rt = 0; rt < 4; ++rt) {
#pragma unroll
            for (int i = 0; i < 4; ++i) {
                const int row = rt * 16 + g * 4 + i;
                hs[row * HSS + c0] = (__bf16)fmaxf(acc[rt][0][i] + b1r0, 0.f);
                hs[row * HSS + c1] = (__bf16)fmaxf(acc[rt][1][i] + b1r1, 0.f);
            }
        }
        __syncthreads();

        // ---- GEMM2: delta = h @ W2 (W2 frags from LDS) ----
        f32x4 acc2[4][2];
#pragma unroll
        for (int rt = 0; rt < 4; ++rt)
#pragma unroll
            for (int ct = 0; ct < 2; ++ct)
                acc2[rt][ct] = (f32x4){0.f, 0.f, 0.f, 0.f};

        __builtin_amdgcn_s_setprio(1);
#pragma unroll
        for (int ks = 0; ks < 4; ++ks) {
            const bf16x8 wf0 = *(const bf16x8*)(w2w + ks * 1024 + lane * 8);
            const bf16x8 wf1 = *(const bf16x8*)(w2w + ks * 1024 + 512 + lane * 8);
#pragma unroll
            for (int rt = 0; rt < 4; ++rt) {
                const bf16x8 a = *(const bf16x8*)(hs + (rt * 16 + l) * HSS + ks * 32 + g * 8);
                acc2[rt][0] = __builtin_amdgcn_mfma_f32_16x16x32_bf16(a, wf0, acc2[rt][0], 0, 0, 0);
                acc2[rt][1] = __builtin_amdgcn_mfma_f32_16x16x32_bf16(a, wf1, acc2[rt][1], 0, 0, 0);
            }
        }
        __builtin_amdgcn_s_setprio(0);

        // ---- residual: v = x + delta + b2 (x from bf16 LDS tile, row+1) ----
#pragma unroll
        for (int rt = 0; rt < 4; ++rt) {
#pragma unroll
            for (int i = 0; i < 4; ++i) {
                const int row = rt * 16 + g * 4 + i;
                acc2[rt][0][i] += b2r0 + (float)xs[(row + 1) * XS + c0];
                acc2[rt][1][i] += b2r1 + (float)xs[(row + 1) * XS + c1];
            }
        }
        __syncthreads();  // all xs/hs reads done; vs may now clobber them

#pragma unroll
        for (int rt = 0; rt < 4; ++rt) {
#pragma unroll
            for (int i = 0; i < 4; ++i) {
                const int row = rt * 16 + g * 4 + i;
                vs[row * VS + c0] = acc2[rt][0][i];
                vs[row * VS + c1] = acc2[rt][1][i];
            }
        }
        __syncthreads();

        // ---- fused LN: single vs read -> stats in-regs -> normalize + store ----
        {
            const int row = tid >> 2;
            const int q4  = (tid & 3) * 4;    // interleaved chunks: words q4 + 16*c8
            f32x4 vv[8];
            float s = 0.f, qq = 0.f;
#pragma unroll
            for (int c8 = 0; c8 < 8; ++c8) {
                vv[c8] = *(const f32x4*)(vs + row * VS + c8 * 16 + q4);
#pragma unroll
                for (int e = 0; e < 4; ++e) { s += vv[c8][e]; qq += vv[c8][e] * vv[c8][e]; }
            }
            s  += __shfl_xor(s, 1, 4);  s  += __shfl_xor(s, 2, 4);
            qq += __shfl_xor(qq, 1, 4); qq += __shfl_xor(qq, 2, 4);
            const float muv = s * (1.f / 128.f);
            const float var = qq * (1.f / 128.f) - muv * muv;
            const float rv  = rsqrtf(var + 1e-5f);
            float* op = out + (rowbase + n0 + row) * H;
#pragma unroll
            for (int c8 = 0; c8 < 8; ++c8) {
                const f32x4 gm = *(const f32x4*)(s_gamma + c8 * 16 + q4);
                const f32x4 bt = *(const f32x4*)(s_beta  + c8 * 16 + q4);
                f32x4 o;
#pragma unroll
                for (int e = 0; e < 4; ++e)
                    o[e] = fmaxf((vv[c8][e] - muv) * rv * gm[e] + bt[e], 0.f);
                *(f32x4*)(op + c8 * 16 + q4) = o;
            }
        }
    }
}

extern "C" void kernel_launch(void* const* d_in, const int* in_sizes, int n_in,
                              void* d_out, int out_size, void* d_ws, size_t ws_size,
                              hipStream_t stream) {
    const float* x     = (const float*)d_in[0];
    const float* W1    = (const float*)d_in[1];
    const float* b1    = (const float*)d_in[2];
    const float* W2    = (const float*)d_in[3];
    const float* b2    = (const float*)d_in[4];
    const float* gamma = (const float*)d_in[5];
    const float* beta  = (const float*)d_in[6];
    float* out = (float*)d_out;

    // 512 blocks = 2 resident blocks/CU * 256 CUs; grid-stride over 4096 tiles
    cbb_kernel<<<GRID, 256, 0, stream>>>(x, W1, b1, W2, b2, gamma, beta, out);
}

// Round 5
// 263.479 us; speedup vs baseline: 1.3469x; 1.0043x over previous
//
#include <hip/hip_runtime.h>

// Fused CircularBoundaryBlock:
//   out = relu(LN(x + W2 @ relu(W1 @ [roll(x,1), x, roll(x,-1)] + b1) + b2))
// B=4, N=65536, H=128, fp32 I/O, bf16 MFMA internally.
//
// v6 = v5 + swapped-operand MFMA epilogues.
//   mfma(A,B) fragment layouts are m<->n symmetric, so mfma(w_frag, x_frag)
//   computes D[outcol][tilerow] with the SAME register data — each lane then
//   holds 4 CONSECUTIVE output columns of one row. This turns the epilogues
//   from 96 scalar LDS ops/thread/iter (32 ds_write_b16 hs + 32 ds_read_u16
//   residual + 32 ds_write_b32 vs) into 24 vector ops (8 b64 writes + 8 b64
//   reads + 8 b128 writes). VS=132 (mult of 4) keeps b128 stores aligned.
// Everything else identical to v5: W1 frags in regs, W2 frags in LDS (32KB),
// T14 stage split + halo prefetch, fused LN, setprio, 256 thr, 512 blocks.

typedef __bf16 bf16x8 __attribute__((ext_vector_type(8)));
typedef __bf16 bf16x4 __attribute__((ext_vector_type(4)));
typedef float  f32x4  __attribute__((ext_vector_type(4)));

#define H      128
#define NB     65536        // rows per batch
#define TILE   64
#define XS     136          // x LDS stride (bf16 elems)
#define HSS    136          // h LDS stride (bf16 elems)
#define VS     132          // v LDS stride (f32 elems), mult of 4 -> b128 aligned
#define NTILES 4096         // 4 * 65536 / 64
#define GRID   512          // 2 blocks/CU * 256 CUs

__global__ __launch_bounds__(256, 2)
void cbb_kernel(const float* __restrict__ x, const float* __restrict__ W1,
                const float* __restrict__ b1, const float* __restrict__ W2,
                const float* __restrict__ b2, const float* __restrict__ gamma,
                const float* __restrict__ beta, float* __restrict__ out) {
    // region A: xs (66*136 bf16) + hs (64*136 bf16) = 35360 B
    // region B (aliased): vs (64*132 f32) = 33792 B <= 35360 OK
    __shared__ __align__(16) char raw[(66 * XS + 64 * HSS) * 2];
    __bf16* xs = (__bf16*)raw;
    __bf16* hs = xs + 66 * XS;
    float*  vs = (float*)raw;
    __shared__ __align__(16) __bf16 w2s[16384];   // W2 frags, 32 KB, persistent
    __shared__ float s_gamma[128], s_beta[128];

    const int tid  = threadIdx.x;
    const int wid  = tid >> 6;
    const int lane = tid & 63;
    const int l    = lane & 15;   // MFMA n index (tile row, after swap)
    const int g    = lane >> 4;   // MFMA quad
    const int col0 = wid * 32;

    if (tid < 128) { s_gamma[tid] = gamma[tid]; s_beta[tid] = beta[tid]; }

    // per-lane bias quads: output cols col0 + ct*16 + g*4 .. +3
    const f32x4 b1v[2] = { *(const f32x4*)(b1 + col0 + g * 4),
                           *(const f32x4*)(b1 + col0 + 16 + g * 4) };
    const f32x4 b2v[2] = { *(const f32x4*)(b2 + col0 + g * 4),
                           *(const f32x4*)(b2 + col0 + 16 + g * 4) };

    // ---- W1 B-fragments persistent in registers (this wave's 32-col slice) ----
    bf16x8 w1f[12][2];
#pragma unroll
    for (int ks = 0; ks < 12; ++ks) {
#pragma unroll
        for (int ct = 0; ct < 2; ++ct) {
            const int cc = col0 + ct * 16 + l;
            bf16x8 f;
#pragma unroll
            for (int j = 0; j < 8; ++j)
                f[j] = (__bf16)W1[(ks * 32 + g * 8 + j) * H + cc];
            w1f[ks][ct] = f;
        }
    }

    // ---- W2 B-fragments -> LDS, fragment-ordered (once per block) ----
    // layout: w2s[w*4096 + ks*1024 + ct*512 + lane*8 + j]
    for (int idx = tid; idx < 16384; idx += 256) {
        const int j  = idx & 7;
        const int ln = (idx >> 3) & 63;
        const int ct = (idx >> 9) & 1;
        const int ks = (idx >> 10) & 3;
        const int w  = idx >> 12;
        const int row = ks * 32 + (ln >> 4) * 8 + j;
        const int col = w * 32 + ct * 16 + (ln & 15);
        w2s[idx] = (__bf16)W2[row * H + col];
    }
    const __bf16* w2w = w2s + wid * 4096;

    // ---- T14 prefetch: full 66-row halo tile (8 float4 + tid<64 halo) ----
    float4 xreg[8];
    float4 xhalo;
    {
        const int t  = blockIdx.x;
        const int b  = t >> 10;
        const int n0 = (t & 1023) << 6;
        const size_t rowbase = (size_t)b * NB;
#pragma unroll
        for (int s = 0; s < 8; ++s) {
            const int q = tid + s * 256;            // q < 2048 -> rows 0..63
            const int r = q >> 5, c = q & 31;
            const int grow = (n0 - 1 + r + NB) & (NB - 1);
            xreg[s] = *(const float4*)(x + ((rowbase + grow) * H + c * 4));
        }
        if (tid < 64) {                              // rows 64,65
            const int q = 2048 + tid;
            const int r = q >> 5, c = q & 31;
            const int grow = (n0 - 1 + r + NB) & (NB - 1);
            xhalo = *(const float4*)(x + ((rowbase + grow) * H + c * 4));
        }
    }

    for (int t = blockIdx.x; t < NTILES; t += GRID) {
        const int b  = t >> 10;
        const int n0 = (t & 1023) << 6;
        const size_t rowbase = (size_t)b * NB;

        __syncthreads();  // protect vs (aliases xs) from previous iteration readers

        // ---- stage: consume prefetched regs -> xs (bf16) ----
#pragma unroll
        for (int s = 0; s < 8; ++s) {
            const int q = tid + s * 256;
            const int r = q >> 5, c = q & 31;
            bf16x4 v4;
            v4[0] = (__bf16)xreg[s].x; v4[1] = (__bf16)xreg[s].y;
            v4[2] = (__bf16)xreg[s].z; v4[3] = (__bf16)xreg[s].w;
            *(bf16x4*)(xs + r * XS + c * 4) = v4;
        }
        if (tid < 64) {
            const int q = 2048 + tid;
            const int r = q >> 5, c = q & 31;
            bf16x4 v4;
            v4[0] = (__bf16)xhalo.x; v4[1] = (__bf16)xhalo.y;
            v4[2] = (__bf16)xhalo.z; v4[3] = (__bf16)xhalo.w;
            *(bf16x4*)(xs + r * XS + c * 4) = v4;
        }
        __syncthreads();

        // ---- issue next tile's loads; they fly under GEMM1/GEMM2/LN ----
        if (t + GRID < NTILES) {
            const int tn  = t + GRID;
            const int bn  = tn >> 10;
            const int n0n = (tn & 1023) << 6;
            const size_t rbn = (size_t)bn * NB;
#pragma unroll
            for (int s = 0; s < 8; ++s) {
                const int q = tid + s * 256;
                const int r = q >> 5, c = q & 31;
                const int grow = (n0n - 1 + r + NB) & (NB - 1);
                xreg[s] = *(const float4*)(x + ((rbn + grow) * H + c * 4));
            }
            if (tid < 64) {
                const int q = 2048 + tid;
                const int r = q >> 5, c = q & 31;
                const int grow = (n0n - 1 + r + NB) & (NB - 1);
                xhalo = *(const float4*)(x + ((rbn + grow) * H + c * 4));
            }
        }

        // ---- GEMM1 (swapped): acc[rt][ct] = D[hcol quad][tilerow] ----
        f32x4 acc[4][2];
#pragma unroll
        for (int rt = 0; rt < 4; ++rt)
#pragma unroll
            for (int ct = 0; ct < 2; ++ct)
                acc[rt][ct] = (f32x4){0.f, 0.f, 0.f, 0.f};

        __builtin_amdgcn_s_setprio(1);
#pragma unroll
        for (int ks = 0; ks < 12; ++ks) {
            const int k  = ks * 32 + g * 8;          // k in [0,384)
            const int ro = k >> 7, kc = k & 127;
#pragma unroll
            for (int rt = 0; rt < 4; ++rt) {
                const bf16x8 a = *(const bf16x8*)(xs + (rt * 16 + l + ro) * XS + kc);
                acc[rt][0] = __builtin_amdgcn_mfma_f32_16x16x32_bf16(w1f[ks][0], a, acc[rt][0], 0, 0, 0);
                acc[rt][1] = __builtin_amdgcn_mfma_f32_16x16x32_bf16(w1f[ks][1], a, acc[rt][1], 0, 0, 0);
            }
        }
        __builtin_amdgcn_s_setprio(0);

        // relu + bias -> hs: lane holds cols col0+ct*16+g*4..+3 of row rt*16+l
#pragma unroll
        for (int rt = 0; rt < 4; ++rt) {
#pragma unroll
            for (int ct = 0; ct < 2; ++ct) {
                bf16x4 hv;
#pragma unroll
                for (int i = 0; i < 4; ++i)
                    hv[i] = (__bf16)fmaxf(acc[rt][ct][i] + b1v[ct][i], 0.f);
                *(bf16x4*)(hs + (rt * 16 + l) * HSS + col0 + ct * 16 + g * 4) = hv;
            }
        }
        __syncthreads();

        // ---- GEMM2 (swapped): delta[outcol quad][tilerow] ----
        f32x4 acc2[4][2];
#pragma unroll
        for (int rt = 0; rt < 4; ++rt)
#pragma unroll
            for (int ct = 0; ct < 2; ++ct)
                acc2[rt][ct] = (f32x4){0.f, 0.f, 0.f, 0.f};

        __builtin_amdgcn_s_setprio(1);
#pragma unroll
        for (int ks = 0; ks < 4; ++ks) {
            const bf16x8 wf0 = *(const bf16x8*)(w2w + ks * 1024 + lane * 8);
            const bf16x8 wf1 = *(const bf16x8*)(w2w + ks * 1024 + 512 + lane * 8);
#pragma unroll
            for (int rt = 0; rt < 4; ++rt) {
                const bf16x8 a = *(const bf16x8*)(hs + (rt * 16 + l) * HSS + ks * 32 + g * 8);
                acc2[rt][0] = __builtin_amdgcn_mfma_f32_16x16x32_bf16(wf0, a, acc2[rt][0], 0, 0, 0);
                acc2[rt][1] = __builtin_amdgcn_mfma_f32_16x16x32_bf16(wf1, a, acc2[rt][1], 0, 0, 0);
            }
        }
        __builtin_amdgcn_s_setprio(0);

        // ---- residual: v = x + delta + b2 (vectorized b64 x re-read) ----
#pragma unroll
        for (int rt = 0; rt < 4; ++rt) {
#pragma unroll
            for (int ct = 0; ct < 2; ++ct) {
                const bf16x4 xv = *(const bf16x4*)(xs + (rt * 16 + l + 1) * XS + col0 + ct * 16 + g * 4);
#pragma unroll
                for (int i = 0; i < 4; ++i)
                    acc2[rt][ct][i] += b2v[ct][i] + (float)xv[i];
            }
        }
        __syncthreads();  // all xs/hs reads done; vs may now clobber them

        // ---- vs write: one b128 per (rt,ct) ----
#pragma unroll
        for (int rt = 0; rt < 4; ++rt)
#pragma unroll
            for (int ct = 0; ct < 2; ++ct)
                *(f32x4*)(vs + (rt * 16 + l) * VS + col0 + ct * 16 + g * 4) = acc2[rt][ct];
        __syncthreads();

        // ---- fused LN: single vs read -> stats in-regs -> normalize + store ----
        {
            const int row = tid >> 2;
            const int q4  = (tid & 3) * 4;    // interleaved chunks: words q4 + 16*c8
            f32x4 vv[8];
            float s = 0.f, qq = 0.f;
#pragma unroll
            for (int c8 = 0; c8 < 8; ++c8) {
                vv[c8] = *(const f32x4*)(vs + row * VS + c8 * 16 + q4);
#pragma unroll
                for (int e = 0; e < 4; ++e) { s += vv[c8][e]; qq += vv[c8][e] * vv[c8][e]; }
            }
            s  += __shfl_xor(s, 1, 4);  s  += __shfl_xor(s, 2, 4);
            qq += __shfl_xor(qq, 1, 4); qq += __shfl_xor(qq, 2, 4);
            const float muv = s * (1.f / 128.f);
            const float var = qq * (1.f / 128.f) - muv * muv;
            const float rv  = rsqrtf(var + 1e-5f);
            float* op = out + (rowbase + n0 + row) * H;
#pragma unroll
            for (int c8 = 0; c8 < 8; ++c8) {
                const f32x4 gm = *(const f32x4*)(s_gamma + c8 * 16 + q4);
                const f32x4 bt = *(const f32x4*)(s_beta  + c8 * 16 + q4);
                f32x4 o;
#pragma unroll
                for (int e = 0; e < 4; ++e)
                    o[e] = fmaxf((vv[c8][e] - muv) * rv * gm[e] + bt[e], 0.f);
                *(f32x4*)(op + c8 * 16 + q4) = o;
            }
        }
    }
}

extern "C" void kernel_launch(void* const* d_in, const int* in_sizes, int n_in,
                              void* d_out, int out_size, void* d_ws, size_t ws_size,
                              hipStream_t stream) {
    const float* x     = (const float*)d_in[0];
    const float* W1    = (const float*)d_in[1];
    const float* b1    = (const float*)d_in[2];
    const float* W2    = (const float*)d_in[3];
    const float* b2    = (const float*)d_in[4];
    const float* gamma = (const float*)d_in[5];
    const float* beta  = (const float*)d_in[6];
    float* out = (float*)d_out;

    // 512 blocks = 2 resident blocks/CU * 256 CUs; grid-stride over 4096 tiles
    cbb_kernel<<<GRID, 256, 0, stream>>>(x, W1, b1, W2, b2, gamma, beta, out);
}